// Round 2
// baseline (603.099 us; speedup 1.0000x reference)
//
#include <hip/hip_runtime.h>
#include <math.h>

// ---- compile-time tables for the solid-harmonics recurrence ----
constexpr float C00f = 0.28209479177387814f;  // 1/sqrt(4*pi)

// AL[l] = -sqrt((2l+1)/(2l))
constexpr float AL[7] = {0.f,
  -1.22474487139158905f, -1.11803398874989485f, -1.08012344973464354f,
  -1.06066017177982121f, -1.04880884817015154f, -1.04083299973306640f};

// AINV[l][m] = 1/A(l,m), A(l,m)=sqrt((l^2-m^2)/((2l-1)(2l+1))), m<l
constexpr float AINV[7][7] = {
  {0,0,0,0,0,0,0},
  {1.73205080756887729f,0,0,0,0,0,0},
  {1.93649167310370852f,2.23606797749978969f,0,0,0,0,0},
  {1.97202659436653873f,2.09165006633518887f,2.64575131106459059f,0,0,0,0},
  {1.98431348329844304f,2.04939015319191986f,2.29128784747791999f,3.0f,0,0,0},
  {1.98997487421323993f,2.03100960115899020f,2.17124068443428311f,2.48746859276654987f,3.31662479035539985f,0,0},
  {1.99304345718356630f,2.02131499000000000f,2.11394180000000000f,2.30136840000000000f,2.67394840000000000f,3.60555127546398912f,0}
};

// APV[l][m] = A(l-1,m), valid for m <= l-2
constexpr float APV[7][7] = {
  {0,0,0,0,0,0,0},
  {0,0,0,0,0,0,0},
  {0.57735026918962576f,0,0,0,0,0,0},
  {0.51639777949432225f,0.44721359549995794f,0,0,0,0,0},
  {0.50709255283710986f,0.47809144373375745f,0.37796447300922722f,0,0,0,0},
  {0.50395263067896967f,0.48795003647426655f,0.43643578047198484f,0.33333333333333333f,0,0,0},
  {0.50251890762960643f,0.49236596391733095f,0.46056618647183828f,0.40201512610368484f,0.30151134457776363f,0,0}
};

#define APT 4   // atoms per thread in k_accum_c

// ---- K0: zero the 294-float c accumulator in workspace (ws is poisoned 0xAA) ----
__global__ void k_zero(float* __restrict__ cg) {
  int t = blockIdx.x * 256 + threadIdx.x;
  if (t < 294) cg[t] = 0.f;
}

// ---- K1: c[a,row,col] = sum_j f[a,j] * Ypacked[row,col,j]
// Block = 1 wave. Lanes 0-31 accumulate a in {0,1,2}, lanes 32-63 a in {3,4,5}
// of the SAME 32 atoms. Each thread serially accumulates APT atoms into 147
// VGPR partials, then ONE 32-lane shuffle reduction + global atomics at the
// end — DS-ops amortized APT x vs per-atom reduction.
__global__ __launch_bounds__(64) void k_accum_c(const float* __restrict__ xyz,
                                                float* __restrict__ cg, int n) {
  const int lane = threadIdx.x;     // 0..63
  const int li   = lane & 31;       // lane within half
  const int half = lane >> 5;       // 0 -> a base 0, 1 -> a base 3
  const int base_atom = blockIdx.x * (32 * APT);

  float acc[3][49];
  #pragma unroll
  for (int i = 0; i < 3; ++i)
    #pragma unroll
    for (int j = 0; j < 49; ++j) acc[i][j] = 0.f;

  #pragma unroll
  for (int it = 0; it < APT; ++it) {
    int atom = base_atom + it * 32 + li;
    int ji = (atom < n) ? atom : 0;
    float x = xyz[3*ji+0], y = xyz[3*ji+1], z = xyz[3*ji+2];
    float r2 = x*x + y*y + z*z;
    float d  = sqrtf(r2);
    float tcut = 1.f - d * (1.f/6.f);
    float r = (d < 6.f && atom < n) ? tcut*tcut : 0.f;   // invalid lanes -> 0
    float r2c = r2*r2*r2;
    float b0  = half ? (r*r2c) : r;          // f[a] = r * r2^a for this half's a's
    float fa0 = b0, fa1 = b0*r2, fa2 = fa1*r2;

    float vr[2][7], vi[2][7];
    vr[0][0] = C00f; vi[0][0] = 0.f;
    #pragma unroll
    for (int l = 0; l <= 6; ++l) {
      const int cur = l & 1, prv = cur ^ 1;
      if (l > 0) {
        #pragma unroll
        for (int m = 0; m + 2 <= l; ++m) {     // two-term recurrence (prev2 in-place)
          float ai = AINV[l][m], ap = APV[l][m];
          vr[cur][m] = (z*vr[prv][m] - ap*r2*vr[cur][m]) * ai;
          vi[cur][m] = (z*vi[prv][m] - ap*r2*vi[cur][m]) * ai;
        }
        float ai = AINV[l][l-1];               // one-term, m = l-1
        float vpr = vr[prv][l-1], vpi = vi[prv][l-1];
        vr[cur][l-1] = z*vpr*ai;
        vi[cur][l-1] = z*vpi*ai;
        vr[cur][l] = AL[l]*(x*vpr - y*vpi);    // diagonal m = l
        vi[cur][l] = AL[l]*(x*vpi + y*vpr);
      }
      // re(l,m) -> packed (l, l-m); im(l,m>=1) -> packed (m-1, l)
      #pragma unroll
      for (int m = 0; m <= l; ++m) {
        int idx_re = l*7 + (l - m);
        float v = vr[cur][m];
        acc[0][idx_re] += fa0*v; acc[1][idx_re] += fa1*v; acc[2][idx_re] += fa2*v;
        if (m >= 1) {
          int idx_im = (m-1)*7 + l;
          float u = vi[cur][m];
          acc[0][idx_im] += fa0*u; acc[1][idx_im] += fa1*u; acc[2][idx_im] += fa2*u;
        }
      }
    }
  }

  // one 32-lane butterfly per partial, then global atomic from each half's lane 0
  #pragma unroll
  for (int i = 0; i < 3; ++i) {
    #pragma unroll
    for (int j = 0; j < 49; ++j) {
      float v = acc[i][j];
      v += __shfl_xor(v,  1, 32);
      v += __shfl_xor(v,  2, 32);
      v += __shfl_xor(v,  4, 32);
      v += __shfl_xor(v,  8, 32);
      v += __shfl_xor(v, 16, 32);
      if (li == 0) atomicAdd(&cg[(3*half + i)*49 + j], v);
    }
  }
}

// ---- K3: dp[l,a,b,j,k] (+ p[l,a,b] folded into block 0) ----
// One thread per (atom j, component k), tid = 3j+k.
// cs[] in LDS is PRE-WEIGHTED by the Yr/Yi mask (1 on packed diagonal, 2 off),
// stores use 32-bit offsets (SGPR base + voffset), P[a]=dfr[a]*w hoisted.
__global__ __launch_bounds__(256) void k_dp(const float* __restrict__ xyz,
                                            const float* __restrict__ cg,
                                            float* __restrict__ out, int n3) {
  __shared__ float cs[294];
  for (int i = threadIdx.x; i < 294; i += 256) {
    int rc  = i % 49;
    int row = rc / 7, col = rc % 7;
    float wgt = (row == col) ? 1.f : 2.f;   // packed diagonal = re(l,0)
    cs[i] = wgt * cg[i];
  }
  __syncthreads();

  // folded k_p: reads RAW cg from global (252 threads, L2-resident)
  if (blockIdx.x == 0 && threadIdx.x < 252) {
    int t = threadIdx.x;
    int pl = t / 36;
    int rem = t - 36*pl;
    int pa = rem / 6;
    int pb = rem - 6*pa;
    const float* ca = cg + pa*49;
    const float* cb = cg + pb*49;
    float s = 0.f;
    for (int mc = 0; mc <= pl; ++mc) {
      float wq = (mc == pl) ? 1.f : 2.f;
      s += wq * ca[pl*7+mc] * cb[pl*7+mc];
    }
    for (int rr = 0; rr < pl; ++rr)
      s += 2.f * ca[rr*7+pl] * cb[rr*7+pl];
    out[t] = s;
  }

  int tid = blockIdx.x * 256 + threadIdx.x;
  if (tid >= n3) return;
  int j = tid / 3;
  int k = tid - 3*j;
  float x = xyz[3*j+0], y = xyz[3*j+1], z = xyz[3*j+2];
  float ex = (k == 0) ? 1.f : 0.f;
  float ey = (k == 1) ? 1.f : 0.f;
  float ez = (k == 2) ? 1.f : 0.f;
  float pk = ex*x + ey*y + ez*z;       // xyz[k]
  float r2 = x*x + y*y + z*z;
  float d  = sqrtf(r2);
  float invd = (d > 0.f) ? 1.f/d : 0.f;
  bool inside = d < 6.f;
  float tcut = 1.f - d*(1.f/6.f);
  float r  = inside ? tcut*tcut : 0.f;
  float dr = inside ? (-1.f/3.f)*tcut : 0.f;
  float f[6], dfr[6];                  // f[a], dfr[a] = d f[a] / d d
  { float dp = 1.f;
    #pragma unroll
    for (int a = 0; a < 6; ++a) {
      f[a]   = r*dp;
      dfr[a] = dp*(dr + (2.f*a)*r*invd);
      dp *= r2;
    } }
  float w = pk * invd;                 // direction factor xyz[k]/d
  float P[6];
  #pragma unroll
  for (int a = 0; a < 6; ++a) P[a] = dfr[a]*w;   // hoisted out of l-loop

  float* outdp = out + 252;
  const unsigned un3 = (unsigned)n3;
  const unsigned t32 = (unsigned)tid;

  // value + d/dk recurrence, two rows ping-pong (row l-2 overwritten in place)
  float vr[2][7], vi[2][7], gr[2][7], gi[2][7];
  vr[0][0] = C00f; vi[0][0] = 0.f; gr[0][0] = 0.f; gi[0][0] = 0.f;
  #pragma unroll
  for (int l = 0; l <= 6; ++l) {
    const int cur = l & 1, prv = cur ^ 1;
    if (l > 0) {
      #pragma unroll
      for (int m = 0; m + 2 <= l; ++m) {
        float ai = AINV[l][m], ap = APV[l][m];
        float ovr = vr[cur][m], ovi = vi[cur][m];   // row l-2 (read before overwrite)
        float ogr = gr[cur][m], ogi = gi[cur][m];
        vr[cur][m] = (z*vr[prv][m] - ap*r2*ovr) * ai;
        gr[cur][m] = (ez*vr[prv][m] + z*gr[prv][m] - ap*(2.f*pk*ovr + r2*ogr)) * ai;
        vi[cur][m] = (z*vi[prv][m] - ap*r2*ovi) * ai;
        gi[cur][m] = (ez*vi[prv][m] + z*gi[prv][m] - ap*(2.f*pk*ovi + r2*ogi)) * ai;
      }
      { float ai  = AINV[l][l-1];
        float vpr = vr[prv][l-1], vpi = vi[prv][l-1];
        float gpr = gr[prv][l-1], gpi = gi[prv][l-1];
        vr[cur][l-1] = z*vpr*ai;
        gr[cur][l-1] = (ez*vpr + z*gpr)*ai;
        vi[cur][l-1] = z*vpi*ai;
        gi[cur][l-1] = (ez*vpi + z*gpi)*ai;
        vr[cur][l] = AL[l]*(x*vpr - y*vpi);
        gr[cur][l] = AL[l]*(ex*vpr + x*gpr - ey*vpi - y*gpi);
        vi[cur][l] = AL[l]*(x*vpi + y*vpr);
        gi[cur][l] = AL[l]*(ex*vpi + x*gpi + ey*vpr + y*gpr); }
    }
    // G[b] = masked Y*c for degree l; Hh[b] = same with dY/dk (weights pre-folded)
    float G[6]  = {0,0,0,0,0,0};
    float Hh[6] = {0,0,0,0,0,0};
    #pragma unroll
    for (int m = 0; m <= l; ++m) {
      float vv = vr[cur][m], gg = gr[cur][m];
      int base = l*7 + (l - m);
      #pragma unroll
      for (int b = 0; b < 6; ++b) { float cc = cs[b*49 + base]; G[b] += vv*cc; Hh[b] += gg*cc; }
      if (m >= 1) {
        float vv2 = vi[cur][m], gg2 = gi[cur][m];
        int base2 = (m-1)*7 + l;
        #pragma unroll
        for (int b = 0; b < 6; ++b) { float cc = cs[b*49 + base2]; G[b] += vv2*cc; Hh[b] += gg2*cc; }
      }
    }
    // dp[l,a,b] = P[a]G[b] + f[a]H[b] + P[b]G[a] + f[b]H[a]  (symmetric a<->b)
    #pragma unroll
    for (int a = 0; a < 6; ++a) {
      #pragma unroll
      for (int b = a; b < 6; ++b) {
        float val = P[a]*G[b] + f[a]*Hh[b] + P[b]*G[a] + f[b]*Hh[a];
        outdp[(unsigned)(l*36 + a*6 + b)*un3 + t32] = val;
        if (b > a)
          outdp[(unsigned)(l*36 + b*6 + a)*un3 + t32] = val;
      }
    }
  }
}

extern "C" void kernel_launch(void* const* d_in, const int* in_sizes, int n_in,
                              void* d_out, int out_size, void* d_ws, size_t ws_size,
                              hipStream_t stream) {
  const float* xyz = (const float*)d_in[0];
  float* out = (float*)d_out;
  float* cg  = (float*)d_ws;      // 294 floats of scratch for c[a,row,col]
  int n3 = in_sizes[0];           // N*3 = 196608
  int n  = n3 / 3;                // N   = 65536

  k_zero   <<<dim3(2),                          dim3(256), 0, stream>>>(cg);
  k_accum_c<<<dim3((n + 32*APT - 1)/(32*APT)),  dim3(64),  0, stream>>>(xyz, cg, n);
  k_dp     <<<dim3((n3 + 255)/256),             dim3(256), 0, stream>>>(xyz, cg, out, n3);
}

// Round 4
// 245.285 us; speedup vs baseline: 2.4588x; 2.4588x over previous
//
#include <hip/hip_runtime.h>
#include <math.h>

// ---- compile-time tables for the solid-harmonics recurrence ----
constexpr float C00f = 0.28209479177387814f;  // 1/sqrt(4*pi)

// AL[l] = -sqrt((2l+1)/(2l))
constexpr float AL[7] = {0.f,
  -1.22474487139158905f, -1.11803398874989485f, -1.08012344973464354f,
  -1.06066017177982121f, -1.04880884817015154f, -1.04083299973306640f};

// AINV[l][m] = 1/A(l,m), A(l,m)=sqrt((l^2-m^2)/((2l-1)(2l+1))), m<l
constexpr float AINV[7][7] = {
  {0,0,0,0,0,0,0},
  {1.73205080756887729f,0,0,0,0,0,0},
  {1.93649167310370852f,2.23606797749978969f,0,0,0,0,0},
  {1.97202659436653873f,2.09165006633518887f,2.64575131106459059f,0,0,0,0},
  {1.98431348329844304f,2.04939015319191986f,2.29128784747791999f,3.0f,0,0,0},
  {1.98997487421323993f,2.03100960115899020f,2.17124068443428311f,2.48746859276654987f,3.31662479035539985f,0,0},
  {1.99304345718356630f,2.02131499000000000f,2.11394180000000000f,2.30136840000000000f,2.67394840000000000f,3.60555127546398912f,0}
};

// APV[l][m] = A(l-1,m), valid for m <= l-2
constexpr float APV[7][7] = {
  {0,0,0,0,0,0,0},
  {0,0,0,0,0,0,0},
  {0.57735026918962576f,0,0,0,0,0,0},
  {0.51639777949432225f,0.44721359549995794f,0,0,0,0,0},
  {0.50709255283710986f,0.47809144373375745f,0.37796447300922722f,0,0,0,0},
  {0.50395263067896967f,0.48795003647426655f,0.43643578047198484f,0.33333333333333333f,0,0,0},
  {0.50251890762960643f,0.49236596391733095f,0.46056618647183828f,0.40201512610368484f,0.30151134457776363f,0,0}
};

// ---- K0: zero the 294-float c accumulator in workspace (ws is poisoned 0xAA) ----
__global__ void k_zero(float* __restrict__ cg) {
  int t = blockIdx.x * 256 + threadIdx.x;
  if (t < 294) cg[t] = 0.f;
}

// 32-lane reduction (stays inside a half-wave -> ds_swizzle only, 5-deep chain)
__device__ __forceinline__ void red32_acc(float v, float* dst, int li) {
  v += __shfl_xor(v,  1, 32);
  v += __shfl_xor(v,  2, 32);
  v += __shfl_xor(v,  4, 32);
  v += __shfl_xor(v,  8, 32);
  v += __shfl_xor(v, 16, 32);
  if (li == 0) atomicAdd(dst, v);
}

// ---- K1: c[a,row,col] = sum_j f[a,j] * Ypacked[row,col,j]
// (round-1 proven version) Half-wave split: lanes 0-31 handle a in {0,1,2},
// lanes 32-63 handle a in {3,4,5} of the SAME 32 atoms. Per-atom 32-lane
// shuffle reduce into LDS, one global atomic pass at block end.
__global__ __launch_bounds__(256) void k_accum_c(const float* __restrict__ xyz,
                                                 float* __restrict__ cg, int n) {
  __shared__ float cl[294];
  for (int i = threadIdx.x; i < 294; i += 256) cl[i] = 0.f;
  __syncthreads();
  int lane = threadIdx.x & 63;
  int wv   = threadIdx.x >> 6;      // wave in block: 0..3
  int li   = lane & 31;             // lane within half
  int half = lane >> 5;             // 0 -> a base 0, 1 -> a base 3
  int atom = blockIdx.x * 128 + wv * 32 + li;
  int ji = (atom < n) ? atom : 0;
  float x = xyz[3*ji+0], y = xyz[3*ji+1], z = xyz[3*ji+2];
  float r2 = x*x + y*y + z*z;
  float d  = sqrtf(r2);
  float tcut = 1.f - d * (1.f/6.f);
  float r = (d < 6.f && atom < n) ? tcut*tcut : 0.f;   // invalid lanes -> 0
  float r2c  = r2*r2*r2;
  float base = half ? (r*r2c) : r;          // f[a] = r * r2^a for this half's a's
  float fa[3];
  fa[0] = base; fa[1] = base*r2; fa[2] = fa[1]*r2;
  int abase = 3*half;

  float vr[2][7], vi[2][7];
  vr[0][0] = C00f; vi[0][0] = 0.f;
  #pragma unroll
  for (int l = 0; l <= 6; ++l) {
    const int cur = l & 1, prv = cur ^ 1;
    if (l > 0) {
      #pragma unroll
      for (int m = 0; m + 2 <= l; ++m) {      // two-term recurrence (prev2 in-place)
        float ai = AINV[l][m], ap = APV[l][m];
        vr[cur][m] = (z*vr[prv][m] - ap*r2*vr[cur][m]) * ai;
        vi[cur][m] = (z*vi[prv][m] - ap*r2*vi[cur][m]) * ai;
      }
      { float ai = AINV[l][l-1];              // one-term, m = l-1
        float vpr = vr[prv][l-1], vpi = vi[prv][l-1];
        vr[cur][l-1] = z*vpr*ai;
        vi[cur][l-1] = z*vpi*ai;
        vr[cur][l] = AL[l]*(x*vpr - y*vpi);   // diagonal m = l
        vi[cur][l] = AL[l]*(x*vpi + y*vpr); }
    }
    // re(l,m) -> packed (l, l-m); im(l,m>=1) -> packed (m-1, l)
    #pragma unroll
    for (int m = 0; m <= l; ++m) {
      int idx_re = l*7 + (l - m);
      #pragma unroll
      for (int i = 0; i < 3; ++i)
        red32_acc(fa[i]*vr[cur][m], &cl[(abase+i)*49 + idx_re], li);
      if (m >= 1) {
        int idx_im = (m-1)*7 + l;
        #pragma unroll
        for (int i = 0; i < 3; ++i)
          red32_acc(fa[i]*vi[cur][m], &cl[(abase+i)*49 + idx_im], li);
      }
    }
  }
  __syncthreads();
  for (int i = threadIdx.x; i < 294; i += 256) atomicAdd(&cg[i], cl[i]);
}

// ---- K3: dp[l,a,b,j,k] (+ p[l,a,b] folded into block 0) ----
// One thread per (atom j, component k), tid = 3j+k.
// Per-l epilogue stages the 36 planes x 256 columns in LDS, then the block
// cooperatively stores float4 chunks: each wave-store is 1 KB contiguous
// (vs 256 B scattered before) and store-instruction count drops 4x.
__global__ __launch_bounds__(256) void k_dp(const float* __restrict__ xyz,
                                            const float* __restrict__ cg,
                                            float* __restrict__ out, int n3) {
  __shared__ float cs[294];
  __shared__ __align__(16) float sbuf[36 * 256];   // one l's planes for this block
  for (int i = threadIdx.x; i < 294; i += 256) {
    int rc  = i % 49;
    int row = rc / 7, col = rc % 7;
    float wgt = (row == col) ? 1.f : 2.f;   // packed diagonal = re(l,0)
    cs[i] = wgt * cg[i];
  }
  __syncthreads();

  // folded k_p: reads RAW cg from global (252 threads, L2-resident)
  if (blockIdx.x == 0 && threadIdx.x < 252) {
    int t = threadIdx.x;
    int pl = t / 36;
    int rem = t - 36*pl;
    int pa = rem / 6;
    int pb = rem - 6*pa;
    const float* ca = cg + pa*49;
    const float* cb = cg + pb*49;
    float s = 0.f;
    for (int mc = 0; mc <= pl; ++mc) {
      float wq = (mc == pl) ? 1.f : 2.f;
      s += wq * ca[pl*7+mc] * cb[pl*7+mc];
    }
    for (int rr = 0; rr < pl; ++rr)
      s += 2.f * ca[rr*7+pl] * cb[rr*7+pl];
    out[t] = s;
  }

  const int tx  = threadIdx.x;
  int tid = blockIdx.x * 256 + tx;
  // NO early return: all threads must reach the __syncthreads in the l-loop.
  int jj = (tid < n3) ? tid : (n3 - 1);     // clamp; invalid columns never stored
  int j = jj / 3;
  int k = jj - 3*j;
  float x = xyz[3*j+0], y = xyz[3*j+1], z = xyz[3*j+2];
  float ex = (k == 0) ? 1.f : 0.f;
  float ey = (k == 1) ? 1.f : 0.f;
  float ez = (k == 2) ? 1.f : 0.f;
  float pk = ex*x + ey*y + ez*z;       // xyz[k]
  float r2 = x*x + y*y + z*z;
  float d  = sqrtf(r2);
  float invd = (d > 0.f) ? 1.f/d : 0.f;
  bool inside = d < 6.f;
  float tcut = 1.f - d*(1.f/6.f);
  float r  = inside ? tcut*tcut : 0.f;
  float dr = inside ? (-1.f/3.f)*tcut : 0.f;
  float f[6], dfr[6];                  // f[a], dfr[a] = d f[a] / d d
  { float dp = 1.f;
    #pragma unroll
    for (int a = 0; a < 6; ++a) {
      f[a]   = r*dp;
      dfr[a] = dp*(dr + (2.f*a)*r*invd);
      dp *= r2;
    } }
  float w = pk * invd;                 // direction factor xyz[k]/d
  float P[6];
  #pragma unroll
  for (int a = 0; a < 6; ++a) P[a] = dfr[a]*w;   // hoisted out of l-loop

  float* outdp = out + 252;
  const unsigned un3 = (unsigned)n3;
  const int sub = tx >> 6;                 // plane subgroup 0..3 for coop store
  const int ln  = tx & 63;
  const unsigned colbase = (unsigned)blockIdx.x * 256u + ((unsigned)ln << 2);
  const bool n3mul4 = (un3 & 3u) == 0u;

  // value + d/dk recurrence, two rows ping-pong (row l-2 overwritten in place)
  float vr[2][7], vi[2][7], gr[2][7], gi[2][7];
  vr[0][0] = C00f; vi[0][0] = 0.f; gr[0][0] = 0.f; gi[0][0] = 0.f;
  #pragma unroll
  for (int l = 0; l <= 6; ++l) {
    const int cur = l & 1, prv = cur ^ 1;
    if (l > 0) {
      #pragma unroll
      for (int m = 0; m + 2 <= l; ++m) {
        float ai = AINV[l][m], ap = APV[l][m];
        float ovr = vr[cur][m], ovi = vi[cur][m];   // row l-2 (read before overwrite)
        float ogr = gr[cur][m], ogi = gi[cur][m];
        vr[cur][m] = (z*vr[prv][m] - ap*r2*ovr) * ai;
        gr[cur][m] = (ez*vr[prv][m] + z*gr[prv][m] - ap*(2.f*pk*ovr + r2*ogr)) * ai;
        vi[cur][m] = (z*vi[prv][m] - ap*r2*ovi) * ai;
        gi[cur][m] = (ez*vi[prv][m] + z*gi[prv][m] - ap*(2.f*pk*ovi + r2*ogi)) * ai;
      }
      { float ai  = AINV[l][l-1];
        float vpr = vr[prv][l-1], vpi = vi[prv][l-1];
        float gpr = gr[prv][l-1], gpi = gi[prv][l-1];
        vr[cur][l-1] = z*vpr*ai;
        gr[cur][l-1] = (ez*vpr + z*gpr)*ai;
        vi[cur][l-1] = z*vpi*ai;
        gi[cur][l-1] = (ez*vpi + z*gpi)*ai;
        vr[cur][l] = AL[l]*(x*vpr - y*vpi);
        gr[cur][l] = AL[l]*(ex*vpr + x*gpr - ey*vpi - y*gpi);
        vi[cur][l] = AL[l]*(x*vpi + y*vpr);
        gi[cur][l] = AL[l]*(ex*vpi + x*gpi + ey*vpr + y*gpr); }
    }
    // G[b] = masked Y*c for degree l; Hh[b] = same with dY/dk (weights pre-folded)
    float G[6]  = {0,0,0,0,0,0};
    float Hh[6] = {0,0,0,0,0,0};
    #pragma unroll
    for (int m = 0; m <= l; ++m) {
      float vv = vr[cur][m], gg = gr[cur][m];
      int base = l*7 + (l - m);
      #pragma unroll
      for (int b = 0; b < 6; ++b) { float cc = cs[b*49 + base]; G[b] += vv*cc; Hh[b] += gg*cc; }
      if (m >= 1) {
        float vv2 = vi[cur][m], gg2 = gi[cur][m];
        int base2 = (m-1)*7 + l;
        #pragma unroll
        for (int b = 0; b < 6; ++b) { float cc = cs[b*49 + base2]; G[b] += vv2*cc; Hh[b] += gg2*cc; }
      }
    }
    // stage dp[l,a,b] for this block's 256 columns into LDS (symmetric a<->b)
    #pragma unroll
    for (int a = 0; a < 6; ++a) {
      #pragma unroll
      for (int b = a; b < 6; ++b) {
        float val = P[a]*G[b] + f[a]*Hh[b] + P[b]*G[a] + f[b]*Hh[a];
        sbuf[(a*6 + b)*256 + tx] = val;
        if (b > a) sbuf[(b*6 + a)*256 + tx] = val;
      }
    }
    __syncthreads();
    // cooperative store: 4 planes per pass (one per 64-lane subgroup), 9 passes;
    // each wave-store covers 1 KB contiguous of one plane.
    #pragma unroll
    for (int g = 0; g < 9; ++g) {
      int p = g*4 + sub;                         // 0..35
      const float* sp = &sbuf[p*256 + (ln << 2)];
      unsigned plane = (unsigned)(l*36 + p);
      if (n3mul4) {
        if (colbase + 4 <= un3) {
          float4 v = *reinterpret_cast<const float4*>(sp);
          *reinterpret_cast<float4*>(outdp + (size_t)plane * un3 + colbase) = v;
        }
      } else {
        #pragma unroll
        for (int q = 0; q < 4; ++q)
          if (colbase + q < un3)
            outdp[(size_t)plane * un3 + colbase + q] = sp[q];
      }
    }
    __syncthreads();
  }
}

extern "C" void kernel_launch(void* const* d_in, const int* in_sizes, int n_in,
                              void* d_out, int out_size, void* d_ws, size_t ws_size,
                              hipStream_t stream) {
  const float* xyz = (const float*)d_in[0];
  float* out = (float*)d_out;
  float* cg  = (float*)d_ws;      // 294 floats of scratch for c[a,row,col]
  int n3 = in_sizes[0];           // N*3 = 196608
  int n  = n3 / 3;                // N   = 65536

  k_zero   <<<dim3(2),               dim3(256), 0, stream>>>(cg);
  k_accum_c<<<dim3((n + 127)/128),   dim3(256), 0, stream>>>(xyz, cg, n);
  k_dp     <<<dim3((n3 + 255)/256),  dim3(256), 0, stream>>>(xyz, cg, out, n3);
}

// Round 5
// 238.036 us; speedup vs baseline: 2.5336x; 1.0305x over previous
//
#include <hip/hip_runtime.h>
#include <math.h>

// ---- compile-time tables for the solid-harmonics recurrence ----
constexpr float C00f = 0.28209479177387814f;  // 1/sqrt(4*pi)

// AL[l] = -sqrt((2l+1)/(2l))
constexpr float AL[7] = {0.f,
  -1.22474487139158905f, -1.11803398874989485f, -1.08012344973464354f,
  -1.06066017177982121f, -1.04880884817015154f, -1.04083299973306640f};

// AINV[l][m] = 1/A(l,m), A(l,m)=sqrt((l^2-m^2)/((2l-1)(2l+1))), m<l
constexpr float AINV[7][7] = {
  {0,0,0,0,0,0,0},
  {1.73205080756887729f,0,0,0,0,0,0},
  {1.93649167310370852f,2.23606797749978969f,0,0,0,0,0},
  {1.97202659436653873f,2.09165006633518887f,2.64575131106459059f,0,0,0,0},
  {1.98431348329844304f,2.04939015319191986f,2.29128784747791999f,3.0f,0,0,0},
  {1.98997487421323993f,2.03100960115899020f,2.17124068443428311f,2.48746859276654987f,3.31662479035539985f,0,0},
  {1.99304345718356630f,2.02131499000000000f,2.11394180000000000f,2.30136840000000000f,2.67394840000000000f,3.60555127546398912f,0}
};

// APV[l][m] = A(l-1,m), valid for m <= l-2
constexpr float APV[7][7] = {
  {0,0,0,0,0,0,0},
  {0,0,0,0,0,0,0},
  {0.57735026918962576f,0,0,0,0,0,0},
  {0.51639777949432225f,0.44721359549995794f,0,0,0,0,0},
  {0.50709255283710986f,0.47809144373375745f,0.37796447300922722f,0,0,0,0},
  {0.50395263067896967f,0.48795003647426655f,0.43643578047198484f,0.33333333333333333f,0,0,0},
  {0.50251890762960643f,0.49236596391733095f,0.46056618647183828f,0.40201512610368484f,0.30151134457776363f,0,0}
};

// packed upper-triangle index for (a<=b), 6x6 -> 21
#define IDX21(a,b) ((a)*(11-(a))/2 + (b))

// ---- K0: zero the 294-float c accumulator in workspace (ws is poisoned 0xAA) ----
__global__ void k_zero(float* __restrict__ cg) {
  int t = blockIdx.x * 256 + threadIdx.x;
  if (t < 294) cg[t] = 0.f;
}

// 32-lane reduction (stays inside a half-wave -> ds_swizzle only, 5-deep chain)
__device__ __forceinline__ void red32_acc(float v, float* dst, int li) {
  v += __shfl_xor(v,  1, 32);
  v += __shfl_xor(v,  2, 32);
  v += __shfl_xor(v,  4, 32);
  v += __shfl_xor(v,  8, 32);
  v += __shfl_xor(v, 16, 32);
  if (li == 0) atomicAdd(dst, v);
}

// ---- K1: c[a,row,col] = sum_j f[a,j] * Ypacked[row,col,j]
// (round-1 proven version) Half-wave split: lanes 0-31 handle a in {0,1,2},
// lanes 32-63 handle a in {3,4,5} of the SAME 32 atoms. Per-atom 32-lane
// shuffle reduce into LDS, one global atomic pass at block end.
__global__ __launch_bounds__(256) void k_accum_c(const float* __restrict__ xyz,
                                                 float* __restrict__ cg, int n) {
  __shared__ float cl[294];
  for (int i = threadIdx.x; i < 294; i += 256) cl[i] = 0.f;
  __syncthreads();
  int lane = threadIdx.x & 63;
  int wv   = threadIdx.x >> 6;      // wave in block: 0..3
  int li   = lane & 31;             // lane within half
  int half = lane >> 5;             // 0 -> a base 0, 1 -> a base 3
  int atom = blockIdx.x * 128 + wv * 32 + li;
  int ji = (atom < n) ? atom : 0;
  float x = xyz[3*ji+0], y = xyz[3*ji+1], z = xyz[3*ji+2];
  float r2 = x*x + y*y + z*z;
  float d  = sqrtf(r2);
  float tcut = 1.f - d * (1.f/6.f);
  float r = (d < 6.f && atom < n) ? tcut*tcut : 0.f;   // invalid lanes -> 0
  float r2c  = r2*r2*r2;
  float base = half ? (r*r2c) : r;          // f[a] = r * r2^a for this half's a's
  float fa[3];
  fa[0] = base; fa[1] = base*r2; fa[2] = fa[1]*r2;
  int abase = 3*half;

  float vr[2][7], vi[2][7];
  vr[0][0] = C00f; vi[0][0] = 0.f;
  #pragma unroll
  for (int l = 0; l <= 6; ++l) {
    const int cur = l & 1, prv = cur ^ 1;
    if (l > 0) {
      #pragma unroll
      for (int m = 0; m + 2 <= l; ++m) {      // two-term recurrence (prev2 in-place)
        float ai = AINV[l][m], ap = APV[l][m];
        vr[cur][m] = (z*vr[prv][m] - ap*r2*vr[cur][m]) * ai;
        vi[cur][m] = (z*vi[prv][m] - ap*r2*vi[cur][m]) * ai;
      }
      { float ai = AINV[l][l-1];              // one-term, m = l-1
        float vpr = vr[prv][l-1], vpi = vi[prv][l-1];
        vr[cur][l-1] = z*vpr*ai;
        vi[cur][l-1] = z*vpi*ai;
        vr[cur][l] = AL[l]*(x*vpr - y*vpi);   // diagonal m = l
        vi[cur][l] = AL[l]*(x*vpi + y*vpr); }
    }
    // re(l,m) -> packed (l, l-m); im(l,m>=1) -> packed (m-1, l)
    #pragma unroll
    for (int m = 0; m <= l; ++m) {
      int idx_re = l*7 + (l - m);
      #pragma unroll
      for (int i = 0; i < 3; ++i)
        red32_acc(fa[i]*vr[cur][m], &cl[(abase+i)*49 + idx_re], li);
      if (m >= 1) {
        int idx_im = (m-1)*7 + l;
        #pragma unroll
        for (int i = 0; i < 3; ++i)
          red32_acc(fa[i]*vi[cur][m], &cl[(abase+i)*49 + idx_im], li);
      }
    }
  }
  __syncthreads();
  for (int i = threadIdx.x; i < 294; i += 256) atomicAdd(&cg[i], cl[i]);
}

// ---- K3: dp[l,a,b,j,k] (+ p[l,a,b] folded into block 0) ----
// 768 columns per block, 768 threads (12 waves), exactly n3/768 = 256 blocks
// = 1 block/CU (perfectly even). Per l, the 21 unique symmetric planes are
// staged into a double-buffered LDS panel; the store phase writes 3 KB
// CONTIGUOUS per plane per block (vs 1 KB before) -> DRAM row locality.
// Double-buffer keeps the pre-barrier vmcnt drain overlapped with compute.
__global__ __launch_bounds__(768) void k_dp(const float* __restrict__ xyz,
                                            const float* __restrict__ cg,
                                            float* __restrict__ out, int n3) {
  __shared__ float cs[294];
  __shared__ __align__(16) float sbuf[2][21 * 768];   // 129 KB double-buffered panel
  const int tx = threadIdx.x;
  for (int i = tx; i < 294; i += 768) {
    int rc  = i % 49;
    int row = rc / 7, col = rc % 7;
    float wgt = (row == col) ? 1.f : 2.f;   // packed diagonal = re(l,0)
    cs[i] = wgt * cg[i];
  }
  __syncthreads();

  // folded k_p: reads RAW cg from global (252 threads, L2-resident)
  if (blockIdx.x == 0 && tx < 252) {
    int t = tx;
    int pl = t / 36;
    int rem = t - 36*pl;
    int pa = rem / 6;
    int pb = rem - 6*pa;
    const float* ca = cg + pa*49;
    const float* cb = cg + pb*49;
    float s = 0.f;
    for (int mc = 0; mc <= pl; ++mc) {
      float wq = (mc == pl) ? 1.f : 2.f;
      s += wq * ca[pl*7+mc] * cb[pl*7+mc];
    }
    for (int rr = 0; rr < pl; ++rr)
      s += 2.f * ca[rr*7+pl] * cb[rr*7+pl];
    out[t] = s;
  }

  int tid = blockIdx.x * 768 + tx;
  // NO early return: all threads must reach the __syncthreads in the l-loop.
  int jj = (tid < n3) ? tid : (n3 - 1);     // clamp; invalid columns never stored
  int j = jj / 3;
  int k = jj - 3*j;
  float x = xyz[3*j+0], y = xyz[3*j+1], z = xyz[3*j+2];
  float ex = (k == 0) ? 1.f : 0.f;
  float ey = (k == 1) ? 1.f : 0.f;
  float ez = (k == 2) ? 1.f : 0.f;
  float pk = ex*x + ey*y + ez*z;       // xyz[k]
  float r2 = x*x + y*y + z*z;
  float d  = sqrtf(r2);
  float invd = (d > 0.f) ? 1.f/d : 0.f;
  bool inside = d < 6.f;
  float tcut = 1.f - d*(1.f/6.f);
  float r  = inside ? tcut*tcut : 0.f;
  float dr = inside ? (-1.f/3.f)*tcut : 0.f;
  float f[6], P[6];                    // f[a]; P[a] = (df[a]/dd) * xyz[k]/d
  float w = pk * invd;
  { float dp = 1.f;
    #pragma unroll
    for (int a = 0; a < 6; ++a) {
      f[a] = r*dp;
      P[a] = dp*(dr + (2.f*a)*r*invd) * w;
      dp *= r2;
    } }

  float* outdp = out + 252;
  const unsigned un3 = (unsigned)n3;
  const int wvi = tx >> 6;                 // wave index 0..11
  const int ln  = tx & 63;
  const unsigned colblk = (unsigned)blockIdx.x * 768u;

  // per-wave store planes: p = wvi*3 + g (g = 0..2); packed symmetric index
  // value + d/dk recurrence, two rows ping-pong (row l-2 overwritten in place)
  float vr[2][7], vi[2][7], gr[2][7], gi[2][7];
  vr[0][0] = C00f; vi[0][0] = 0.f; gr[0][0] = 0.f; gi[0][0] = 0.f;
  #pragma unroll
  for (int l = 0; l <= 6; ++l) {
    const int cur = l & 1, prv = cur ^ 1;
    if (l > 0) {
      #pragma unroll
      for (int m = 0; m + 2 <= l; ++m) {
        float ai = AINV[l][m], ap = APV[l][m];
        float ovr = vr[cur][m], ovi = vi[cur][m];   // row l-2 (read before overwrite)
        float ogr = gr[cur][m], ogi = gi[cur][m];
        vr[cur][m] = (z*vr[prv][m] - ap*r2*ovr) * ai;
        gr[cur][m] = (ez*vr[prv][m] + z*gr[prv][m] - ap*(2.f*pk*ovr + r2*ogr)) * ai;
        vi[cur][m] = (z*vi[prv][m] - ap*r2*ovi) * ai;
        gi[cur][m] = (ez*vi[prv][m] + z*gi[prv][m] - ap*(2.f*pk*ovi + r2*ogi)) * ai;
      }
      { float ai  = AINV[l][l-1];
        float vpr = vr[prv][l-1], vpi = vi[prv][l-1];
        float gpr = gr[prv][l-1], gpi = gi[prv][l-1];
        vr[cur][l-1] = z*vpr*ai;
        gr[cur][l-1] = (ez*vpr + z*gpr)*ai;
        vi[cur][l-1] = z*vpi*ai;
        gi[cur][l-1] = (ez*vpi + z*gpi)*ai;
        vr[cur][l] = AL[l]*(x*vpr - y*vpi);
        gr[cur][l] = AL[l]*(ex*vpr + x*gpr - ey*vpi - y*gpi);
        vi[cur][l] = AL[l]*(x*vpi + y*vpr);
        gi[cur][l] = AL[l]*(ex*vpi + x*gpi + ey*vpr + y*gpr); }
    }
    // G[b] = masked Y*c for degree l; Hh[b] = same with dY/dk (weights pre-folded)
    float G[6]  = {0,0,0,0,0,0};
    float Hh[6] = {0,0,0,0,0,0};
    #pragma unroll
    for (int m = 0; m <= l; ++m) {
      float vv = vr[cur][m], gg = gr[cur][m];
      int base = l*7 + (l - m);
      #pragma unroll
      for (int b = 0; b < 6; ++b) { float cc = cs[b*49 + base]; G[b] += vv*cc; Hh[b] += gg*cc; }
      if (m >= 1) {
        float vv2 = vi[cur][m], gg2 = gi[cur][m];
        int base2 = (m-1)*7 + l;
        #pragma unroll
        for (int b = 0; b < 6; ++b) { float cc = cs[b*49 + base2]; G[b] += vv2*cc; Hh[b] += gg2*cc; }
      }
    }
    // stage the 21 unique symmetric planes for this block's 768 columns
    float* sb = sbuf[cur];
    #pragma unroll
    for (int a = 0; a < 6; ++a) {
      #pragma unroll
      for (int b = a; b < 6; ++b) {
        float val = P[a]*G[b] + f[a]*Hh[b] + P[b]*G[a] + f[b]*Hh[a];
        sb[IDX21(a,b)*768 + tx] = val;
      }
    }
    __syncthreads();
    // cooperative store: wave wvi stores planes p = wvi*3+g, each 768 floats
    // = 3 dwordx4 per lane -> 3 KB contiguous per plane per block.
    #pragma unroll
    for (int g = 0; g < 3; ++g) {
      int p  = wvi*3 + g;                 // 0..35
      int pa = p / 6, pb = p - 6*pa;
      int lo = pa < pb ? pa : pb;
      int hi = pa < pb ? pb : pa;
      const float* sp = &sb[IDX21(lo,hi)*768];
      size_t planeoff = (size_t)(l*36 + p) * (size_t)un3;
      #pragma unroll
      for (int q = 0; q < 3; ++q) {
        unsigned coff = (unsigned)(q*256 + (ln << 2));
        unsigned col  = colblk + coff;
        if (col + 4 <= un3) {
          float4 v = *reinterpret_cast<const float4*>(sp + coff);
          *reinterpret_cast<float4*>(outdp + planeoff + col) = v;
        } else {
          #pragma unroll
          for (int qq = 0; qq < 4; ++qq)
            if (col + qq < un3) outdp[planeoff + col + qq] = sp[coff + qq];
        }
      }
    }
    // no second barrier: next l writes the OTHER buffer; the next iteration's
    // barrier (with its lgkmcnt drain) orders reads-of-this-buffer vs the
    // rewrite at l+2.
  }
}

extern "C" void kernel_launch(void* const* d_in, const int* in_sizes, int n_in,
                              void* d_out, int out_size, void* d_ws, size_t ws_size,
                              hipStream_t stream) {
  const float* xyz = (const float*)d_in[0];
  float* out = (float*)d_out;
  float* cg  = (float*)d_ws;      // 294 floats of scratch for c[a,row,col]
  int n3 = in_sizes[0];           // N*3 = 196608
  int n  = n3 / 3;                // N   = 65536

  k_zero   <<<dim3(2),               dim3(256), 0, stream>>>(cg);
  k_accum_c<<<dim3((n + 127)/128),   dim3(256), 0, stream>>>(xyz, cg, n);
  k_dp     <<<dim3((n3 + 767)/768),  dim3(768), 0, stream>>>(xyz, cg, out, n3);
}